// Round 2
// baseline (368.004 us; speedup 1.0000x reference)
//
#include <hip/hip_runtime.h>

// MultiHeadSelfAttention: BS=4, S=2048, DIM=768, H=12, DH=64
// R4: barrier-free attention — each wave owns 32 queries end-to-end.
//     P redistribution via PRIVATE per-wave LDS strip (same-wave RAW -> lgkmcnt only,
//     no __syncthreads in the main loop). alphas/invs stay in registers (shuffle-reduce
//     leaves them in all lanes). Chunked XCD swizzle on attn grid for K/V L2 locality.
//     Proj/convert side unchanged from R3 (fused QKV launch, XCD swizzle).
// MFMA layouts (learn_hip m89/m91): A/B-frag: [m|n = lane&15][k = quad*8+j]
//                                   C/D: col = lane&15, row = quad*4 + reg

#define BSZ 4
#define SEQ 2048
#define DIMD 768
#define NHD 12
#define MTOT (BSZ*SEQ)      // 8192
#define WELEM (DIMD*DIMD)   // 589824

typedef __bf16 bf16;
typedef __attribute__((ext_vector_type(8))) __bf16 bf16x8;
typedef __attribute__((ext_vector_type(4))) __bf16 bf16x4;
typedef __attribute__((ext_vector_type(4))) float f32x4;

__device__ __forceinline__ f32x4 mfma_bf16(bf16x8 a, bf16x8 b, f32x4 c) {
    return __builtin_amdgcn_mfma_f32_16x16x32_bf16(a, b, c, 0, 0, 0);
}

__device__ __forceinline__ void async16(const bf16* g, bf16* l) {
    __builtin_amdgcn_global_load_lds(
        (const __attribute__((address_space(1))) unsigned int*)g,
        (__attribute__((address_space(3))) unsigned int*)l, 16, 0, 0);
}

// ---------------- converts ----------------
__global__ __launch_bounds__(256) void convert_w_kernel(
    const float* __restrict__ w0, const float* __restrict__ w1,
    const float* __restrict__ w2, const float* __restrict__ w3,
    bf16* __restrict__ out) {
    const int z = blockIdx.y;
    const float* src = (z == 0) ? w0 : (z == 1) ? w1 : (z == 2) ? w2 : w3;
    const int i = (blockIdx.x * 256 + threadIdx.x) * 4;
    float4 v = *(const float4*)(src + i);
    bf16x4 o;
    o[0] = (bf16)v.x; o[1] = (bf16)v.y; o[2] = (bf16)v.z; o[3] = (bf16)v.w;
    *(bf16x4*)(out + (size_t)z * WELEM + i) = o;
}

__global__ __launch_bounds__(256) void convert_x_kernel(
    const float* __restrict__ x0, const float* __restrict__ x1,
    const float* __restrict__ x2,
    bf16* __restrict__ d0, bf16* __restrict__ d1, bf16* __restrict__ d2) {
    const int z = blockIdx.y;
    const float* src = (z == 0) ? x0 : (z == 1) ? x1 : x2;
    bf16* dst = (z == 0) ? d0 : (z == 1) ? d1 : d2;
    const int i = (blockIdx.x * 256 + threadIdx.x) * 4;
    float4 v = *(const float4*)(src + i);
    bf16x4 o;
    o[0] = (bf16)v.x; o[1] = (bf16)v.y; o[2] = (bf16)v.z; o[3] = (bf16)v.w;
    *(bf16x4*)(dst + i) = o;
}

// ---------------- shared 128x128xK768 GEMM core ----------------
__device__ __forceinline__ void gemm_core_768(
    const bf16* __restrict__ Ag, const bf16* __restrict__ Bg,
    int m0, int n0, bf16* As, bf16* Bs, f32x4 (&acc)[4][4]) {
    const int tid = threadIdx.x;
    const int lane = tid & 63, wv = tid >> 6;
    const int quad = lane >> 4, l16 = lane & 15;
    const int wr = wv >> 1, wc = wv & 1;
    const int rr = lane >> 3, cbl = lane & 7;
    const int swz = l16 & 7;
    for (int kt = 0; kt < 12; ++kt) {
        if (kt) __syncthreads();                  // prior frag reads done
        for (int c = 0; c < 4; ++c) {
            const int row = c * 32 + wv * 8 + rr;
            const int cb = cbl ^ (row & 7);       // swizzled source col-block
            const size_t gcol = (size_t)kt * 64 + cb * 8;
            async16(Ag + (size_t)(m0 + row) * 768 + gcol, As + row * 64 + cbl * 8);
            async16(Bg + (size_t)(n0 + row) * 768 + gcol, Bs + row * 64 + cbl * 8);
        }
        __syncthreads();                          // drains vmcnt, LDS visible
        for (int ks = 0; ks < 2; ++ks) {
            bf16x8 af[4], bfr[4];
            for (int t = 0; t < 4; ++t)
                af[t] = *(const bf16x8*)(As + (wr * 64 + t * 16 + l16) * 64 +
                                         (((ks * 4 + quad) ^ swz) * 8));
            for (int t = 0; t < 4; ++t)
                bfr[t] = *(const bf16x8*)(Bs + (wc * 64 + t * 16 + l16) * 64 +
                                          (((ks * 4 + quad) ^ swz) * 8));
            for (int ti = 0; ti < 4; ++ti)
                for (int tj = 0; tj < 4; ++tj)
                    acc[ti][tj] = mfma_bf16(af[ti], bfr[tj], acc[ti][tj]);
        }
    }
}

// ---------------- fused QKV projection ----------------
__global__ __launch_bounds__(256, 3) void proj_kernel(
    const bf16* __restrict__ Xq, const bf16* __restrict__ Xk, const bf16* __restrict__ Xv,
    const bf16* __restrict__ W,
    const float* __restrict__ bq, const float* __restrict__ bk, const float* __restrict__ bv,
    bf16* __restrict__ Qo, bf16* __restrict__ Ko, bf16* __restrict__ Vo) {
    __shared__ __align__(16) bf16 smem[2 * 128 * 64];
    bf16* As = smem;
    bf16* Bs = smem + 128 * 64;
    const int lin = blockIdx.x;
    const int swzb = (lin & 7) * 144 + (lin >> 3);      // bijective: 1152 % 8 == 0
    const int z = swzb / 384;
    const int rem = swzb - z * 384;
    const int rt = rem / 6;                             // row tile (0..63)
    const int xt = rem - rt * 6;                        // feature tile (0..5)
    const bf16* X = (z == 0) ? Xq : (z == 1) ? Xk : Xv;
    const bf16* Wz = W + (size_t)z * WELEM;
    const float* bias = (z == 0) ? bq : (z == 1) ? bk : bv;
    bf16* Out = (z == 0) ? Qo : (z == 1) ? Ko : Vo;

    const int tid = threadIdx.x;
    const int lane = tid & 63, wv = tid >> 6;
    const int quad = lane >> 4, l16 = lane & 15;
    const int wr = wv >> 1, wc = wv & 1;
    f32x4 acc[4][4] = {};
    int m0, n0;
    const bf16 *Ag, *Bg;
    if (z < 2) { m0 = xt * 128; n0 = rt * 128; Ag = Wz; Bg = X; }
    else       { m0 = rt * 128; n0 = xt * 128; Ag = X;  Bg = Wz; }
    gemm_core_768(Ag, Bg, m0, n0, As, Bs, acc);
    __syncthreads();                              // As/Bs reads done; reuse as Ot
    bf16* Ot = smem;                              // 128x128 bf16 tile
    if (z < 2) {
        const float scale = (z == 0) ? 0.125f : 1.0f;
        for (int ti = 0; ti < 4; ++ti) {
            const int featl = wr * 64 + ti * 16 + quad * 4;
            const float4 b4 = *(const float4*)(bias + m0 + featl);
            for (int tj = 0; tj < 4; ++tj) {
                const int sl = wc * 64 + tj * 16 + l16;
                bf16x4 pk;
                pk[0] = (bf16)((acc[ti][tj][0] + b4.x) * scale);
                pk[1] = (bf16)((acc[ti][tj][1] + b4.y) * scale);
                pk[2] = (bf16)((acc[ti][tj][2] + b4.z) * scale);
                pk[3] = (bf16)((acc[ti][tj][3] + b4.w) * scale);
                *(bf16x4*)&Ot[sl * 128 + featl] = pk;   // Ot[s][feat]
            }
        }
        __syncthreads();
        for (int it = 0; it < 8; ++it) {
            const int unit = it * 256 + tid;      // 16B units of the tile
            const int s = unit >> 4, u = unit & 15;
            const int feat = m0 + u * 8;
            const int hh = feat >> 6, dh = feat & 63;
            const int srow = n0 + s;
            const int bb = srow >> 11, s2 = srow & 2047;
            *(bf16x8*)&Out[((size_t)(bb * NHD + hh) * SEQ + s2) * 64 + dh] =
                *(const bf16x8*)&Ot[s * 128 + u * 8];
        }
    } else {
        for (int ti = 0; ti < 4; ++ti) {
            const int sl = wr * 64 + ti * 16 + quad * 4;
            for (int tj = 0; tj < 4; ++tj) {
                const int featl = wc * 64 + tj * 16 + l16;
                const float bv = bias[n0 + featl];
                bf16x4 pk;
                pk[0] = (bf16)(acc[ti][tj][0] + bv);
                pk[1] = (bf16)(acc[ti][tj][1] + bv);
                pk[2] = (bf16)(acc[ti][tj][2] + bv);
                pk[3] = (bf16)(acc[ti][tj][3] + bv);
                *(bf16x4*)&Ot[featl * 128 + sl] = pk;   // Ot[feat][s]
            }
        }
        __syncthreads();
        const int bb = m0 >> 11, sbase = m0 & 2047;
        for (int it = 0; it < 8; ++it) {
            const int unit = it * 256 + tid;
            const int fl = unit >> 4, u = unit & 15;
            const int feat = n0 + fl;
            const int hh = feat >> 6, dh = feat & 63;
            *(bf16x8*)&Out[((size_t)(bb * NHD + hh) * 64 + dh) * SEQ + sbase + u * 8] =
                *(const bf16x8*)&Ot[fl * 128 + u * 8];
        }
    }
}

// ---------------- flash attention (barrier-free) ----------------
// grid 768 = (b,h,qt) flattened + chunked XCD swizzle (96 consecutive per XCD ->
// 6 full (b,h) K/V sets per XCD L2). block 256 = 4 independent waves; each wave
// owns 32 queries (2 strips of 16). Per KV-tile (64 keys), per wave:
//   K frags (8), V frags (8) from global; 16 QK MFMAs; in-register softmax
//   (shuffle-reduce leaves max/sum/alpha in all lanes); P -> private per-wave LDS
//   strip (same-wave RAW, lgkmcnt only, NO barrier); 4 P-frag reads; 16 PV MFMAs.
__global__ __launch_bounds__(256, 3) void attn_kernel(
    const bf16* __restrict__ Qb, const bf16* __restrict__ Kb, const bf16* __restrict__ Vb,
    const int* __restrict__ mask, bf16* __restrict__ CTX) {
    __shared__ __align__(16) bf16 Ps[4][32][72];   // per-wave private strips
    __shared__ int anyz_s;
    const int tid = threadIdx.x;
    const int lane = tid & 63, wv = tid >> 6, quad = lane >> 4, l16 = lane & 15;
    // chunked XCD swizzle over 768 blocks (768 % 8 == 0)
    const int lin = blockIdx.x;
    const int nb = (lin & 7) * 96 + (lin >> 3);
    const int qt = nb & 15;
    const int bh = nb >> 4;                  // 0..47
    const int b = bh / NHD, h = bh - b * NHD;
    if (tid == 0) anyz_s = 0;
    __syncthreads();
    {
        int4 m0v = *(const int4*)(mask + b * SEQ + tid * 8);
        int4 m1v = *(const int4*)(mask + b * SEQ + tid * 8 + 4);
        if (!(m0v.x && m0v.y && m0v.z && m0v.w && m1v.x && m1v.y && m1v.z && m1v.w))
            anyz_s = 1;
    }
    // loop-invariant Q fragments (B operand), 2 strips of 16 queries
    bf16x8 qf0[2], qf1[2];
    for (int st = 0; st < 2; ++st) {
        const bf16* qp = Qb + ((size_t)bh * SEQ + qt * 128 + wv * 32 + st * 16 + l16) * 64;
        qf0[st] = *(const bf16x8*)(qp + quad * 8);
        qf1[st] = *(const bf16x8*)(qp + 32 + quad * 8);
    }
    const bf16* Kp = Kb + (size_t)bh * SEQ * 64 + (size_t)l16 * 64 + quad * 8;
    const bf16* Vp = Vb + (size_t)bh * 64 * SEQ + (size_t)l16 * SEQ + quad * 8;
    const int* Mp = mask + b * SEQ;
    bf16* Pw = &Ps[wv][0][0];                // private 32x72 strip
    f32x4 acc[2][4] = {};                    // [strip][dh-block]
    float rm[2] = {-1e30f, -1e30f}, rs[2] = {0.f, 0.f};
    __syncthreads();                         // anyz_s visible (only barrier besides this)
    const int az = anyz_s;

    for (int kt = 0; kt < SEQ / 64; ++kt) {
        const int k0 = kt * 64;
        // K fragments (A operand: m=key, k=dh), V^T fragments (A: m=dh, k=key)
        bf16x8 kf0[4], kf1[4];
        #pragma unroll
        for (int jj = 0; jj < 4; ++jj) {
            const bf16* kp = Kp + (size_t)(k0 + jj * 16) * 64;
            kf0[jj] = *(const bf16x8*)kp;
            kf1[jj] = *(const bf16x8*)(kp + 32);
        }
        bf16x8 vf[4][2];
        #pragma unroll
        for (int d = 0; d < 4; ++d)
            #pragma unroll
            for (int kb = 0; kb < 2; ++kb)
                vf[d][kb] = *(const bf16x8*)(Vp + (size_t)d * 16 * SEQ + k0 + kb * 32);
        // per-strip: QK^T, softmax, P store, acc rescale
        #pragma unroll
        for (int st = 0; st < 2; ++st) {
            f32x4 sc[4];
            #pragma unroll
            for (int jj = 0; jj < 4; ++jj) {
                f32x4 zf = {};
                zf = mfma_bf16(kf0[jj], qf0[st], zf);
                sc[jj] = mfma_bf16(kf1[jj], qf1[st], zf);
            }
            if (az) {
                #pragma unroll
                for (int jj = 0; jj < 4; ++jj) {
                    const int4 mm = *(const int4*)(Mp + k0 + jj * 16 + quad * 4);
                    sc[jj][0] += mm.x ? 0.f : -1e30f;
                    sc[jj][1] += mm.y ? 0.f : -1e30f;
                    sc[jj][2] += mm.z ? 0.f : -1e30f;
                    sc[jj][3] += mm.w ? 0.f : -1e30f;
                }
            }
            float tmax = -1e30f;
            #pragma unroll
            for (int jj = 0; jj < 4; ++jj)
                #pragma unroll
                for (int r = 0; r < 4; ++r) tmax = fmaxf(tmax, sc[jj][r]);
            tmax = fmaxf(tmax, __shfl_xor(tmax, 16));
            tmax = fmaxf(tmax, __shfl_xor(tmax, 32));
            const float nmax = fmaxf(rm[st], tmax);
            const float alpha = __expf(rm[st] - nmax);
            rm[st] = nmax;
            float tsum = 0.f;
            #pragma unroll
            for (int jj = 0; jj < 4; ++jj) {
                bf16x4 pk;
                #pragma unroll
                for (int r = 0; r < 4; ++r) {
                    const float p = __expf(sc[jj][r] - nmax);
                    tsum += p;
                    pk[r] = (bf16)p;
                }
                *(bf16x4*)&Pw[(st * 16 + l16) * 72 + jj * 16 + quad * 4] = pk;
            }
            tsum += __shfl_xor(tsum, 16);
            tsum += __shfl_xor(tsum, 32);
            rs[st] = rs[st] * alpha + tsum;
            #pragma unroll
            for (int d = 0; d < 4; ++d) {
                acc[st][d][0] *= alpha; acc[st][d][1] *= alpha;
                acc[st][d][2] *= alpha; acc[st][d][3] *= alpha;
            }
        }
        // P fragments (B operand: n=query, k=key) from private strip; PV MFMAs
        bf16x8 pf[2][2];
        #pragma unroll
        for (int st = 0; st < 2; ++st)
            #pragma unroll
            for (int kb = 0; kb < 2; ++kb)
                pf[st][kb] = *(const bf16x8*)&Pw[(st * 16 + l16) * 72 + kb * 32 + quad * 8];
        #pragma unroll
        for (int st = 0; st < 2; ++st)
            #pragma unroll
            for (int kb = 0; kb < 2; ++kb)
                #pragma unroll
                for (int d = 0; d < 4; ++d)
                    acc[st][d] = mfma_bf16(vf[d][kb], pf[st][kb], acc[st][d]);
    }

    // epilogue: normalize (sum already in all lanes) and store
    #pragma unroll
    for (int st = 0; st < 2; ++st) {
        const float inv = 1.0f / rs[st];
        const int s = qt * 128 + wv * 32 + st * 16 + l16;
        #pragma unroll
        for (int d = 0; d < 4; ++d) {
            bf16x4 pk;
            #pragma unroll
            for (int r = 0; r < 4; ++r) pk[r] = (bf16)(acc[st][d][r] * inv);
            *(bf16x4*)&CTX[(size_t)(b * SEQ + s) * DIMD + h * 64 + d * 16 + quad * 4] = pk;
        }
    }
}

// ---------------- output projection (XCD-swizzled, ctx-panel-sharing order) ----------------
__global__ __launch_bounds__(256, 3) void oproj_kernel(
    const bf16* __restrict__ ctx, const bf16* __restrict__ wo,
    const float* __restrict__ bo, float* __restrict__ out) {
    __shared__ __align__(16) bf16 smem[2 * 128 * 64];
    const int lin = blockIdx.x;
    const int swzb = (lin & 7) * 48 + (lin >> 3);       // bijective: 384 % 8 == 0
    const int rt = swzb / 6;                            // ctx row tile (0..63)
    const int xt = swzb - rt * 6;                       // feature tile (0..5)
    const int tid = threadIdx.x;
    const int lane = tid & 63, wv = tid >> 6;
    const int quad = lane >> 4, l16 = lane & 15;
    const int wr = wv >> 1, wc = wv & 1;
    const int m0 = rt * 128, n0 = xt * 128;
    f32x4 acc[4][4] = {};
    gemm_core_768(ctx, wo, m0, n0, smem, smem + 128 * 64, acc);
    for (int ti = 0; ti < 4; ++ti) {
        const int rowb = m0 + wr * 64 + ti * 16 + quad * 4;
        for (int tj = 0; tj < 4; ++tj) {
            const int feat = n0 + wc * 64 + tj * 16 + l16;
            const float bv = bo[feat];
            for (int r = 0; r < 4; ++r)
                out[(size_t)(rowb + r) * DIMD + feat] = acc[ti][tj][r] + bv;
        }
    }
}

extern "C" void kernel_launch(void* const* d_in, const int* in_sizes, int n_in,
                              void* d_out, int out_size, void* d_ws, size_t ws_size,
                              hipStream_t stream) {
    const float* query = (const float*)d_in[0];
    const float* key_t = (const float*)d_in[1];
    const float* value = (const float*)d_in[2];
    const int*   mask  = (const int*)d_in[3];
    const float* q_w = (const float*)d_in[4];
    const float* q_b = (const float*)d_in[5];
    const float* k_w = (const float*)d_in[6];
    const float* k_b = (const float*)d_in[7];
    const float* v_w = (const float*)d_in[8];
    const float* v_b = (const float*)d_in[9];
    const float* o_w = (const float*)d_in[10];
    const float* o_b = (const float*)d_in[11];
    float* out = (float*)d_out;

    bf16* ws  = (bf16*)d_ws;
    bf16* W   = ws;                                  // 4 x WELEM
    bf16* XBq = ws + (size_t)4 * WELEM;              // bf16 inputs (all 3 live for fused proj)
    bf16* XBk = XBq + (size_t)MTOT * DIMD;
    bf16* XBv = XBk + (size_t)MTOT * DIMD;
    bf16* Qb  = XBv + (size_t)MTOT * DIMD;           // [b][h][s][dh]
    bf16* Kb  = Qb + (size_t)MTOT * DIMD;            // [b][h][s][dh]
    bf16* Vb  = Kb + (size_t)MTOT * DIMD;            // [b][h][dh][s]
    bf16* CTX = XBq;                                 // alias: XBq dead after proj

    convert_w_kernel<<<dim3(WELEM / 1024, 4), 256, 0, stream>>>(q_w, k_w, v_w, o_w, W);
    convert_x_kernel<<<dim3(MTOT * DIMD / 1024, 3), 256, 0, stream>>>(
        query, key_t, value, XBq, XBk, XBv);

    proj_kernel<<<1152, 256, 0, stream>>>(XBq, XBk, XBv, W, q_b, k_b, v_b, Qb, Kb, Vb);

    attn_kernel<<<768, 256, 0, stream>>>(Qb, Kb, Vb, mask, CTX);
    oproj_kernel<<<384, 256, 0, stream>>>(CTX, W + (size_t)3 * WELEM, o_b, out);
}

// Round 3
// 293.014 us; speedup vs baseline: 1.2559x; 1.2559x over previous
//
#include <hip/hip_runtime.h>

// MultiHeadSelfAttention: BS=4, S=2048, DIM=768, H=12, DH=64
// R5: R2 cooperative attn structure (best measured) + proven grafts:
//     - chunked XCD swizzle on attn grid (R4 counters: FETCH 105MB->18.5MB)
//     - P-tile XOR swizzle (kills the 8-way ds_read_b128 conflict = 9.5M counter)
//     - K tile staged in LDS via global_load_lds dbuf (pre-swizzled source),
//       single barrier per tile preserved
//     - exp2-domain softmax (log2e folded into Q projection scale)
//     - converts fused into one launch
// MFMA layouts (learn_hip m89/m91): A/B-frag: [m|n = lane&15][k = quad*8+j]
//                                   C/D: col = lane&15, row = quad*4 + reg

#define BSZ 4
#define SEQ 2048
#define DIMD 768
#define NHD 12
#define MTOT (BSZ*SEQ)      // 8192
#define WELEM (DIMD*DIMD)   // 589824

typedef __bf16 bf16;
typedef __attribute__((ext_vector_type(8))) __bf16 bf16x8;
typedef __attribute__((ext_vector_type(4))) __bf16 bf16x4;
typedef __attribute__((ext_vector_type(4))) float f32x4;

__device__ __forceinline__ f32x4 mfma_bf16(bf16x8 a, bf16x8 b, f32x4 c) {
    return __builtin_amdgcn_mfma_f32_16x16x32_bf16(a, b, c, 0, 0, 0);
}

__device__ __forceinline__ void async16(const bf16* g, bf16* l) {
    __builtin_amdgcn_global_load_lds(
        (const __attribute__((address_space(1))) unsigned int*)g,
        (__attribute__((address_space(3))) unsigned int*)l, 16, 0, 0);
}

// ---------------- fused converts (one launch) ----------------
// blocks 0..2303: weights (4 x 576); blocks 2304..20735: activations (3 x 6144)
__global__ __launch_bounds__(256) void convert_all_kernel(
    const float* __restrict__ w0, const float* __restrict__ w1,
    const float* __restrict__ w2, const float* __restrict__ w3,
    const float* __restrict__ x0, const float* __restrict__ x1,
    const float* __restrict__ x2,
    bf16* __restrict__ W, bf16* __restrict__ d0, bf16* __restrict__ d1,
    bf16* __restrict__ d2) {
    int id = blockIdx.x;
    const float* src;
    bf16* dst;
    int base;
    if (id < 2304) {
        const int z = id / 576, r = id - z * 576;
        src = (z == 0) ? w0 : (z == 1) ? w1 : (z == 2) ? w2 : w3;
        dst = W + (size_t)z * WELEM;
        base = r * 1024;
    } else {
        id -= 2304;
        const int z = id / 6144, r = id - z * 6144;
        src = (z == 0) ? x0 : (z == 1) ? x1 : x2;
        dst = (z == 0) ? d0 : (z == 1) ? d1 : d2;
        base = r * 1024;
    }
    const int i = base + threadIdx.x * 4;
    float4 v = *(const float4*)(src + i);
    bf16x4 o;
    o[0] = (bf16)v.x; o[1] = (bf16)v.y; o[2] = (bf16)v.z; o[3] = (bf16)v.w;
    *(bf16x4*)(dst + i) = o;
}

// ---------------- shared 128x128xK768 GEMM core ----------------
__device__ __forceinline__ void gemm_core_768(
    const bf16* __restrict__ Ag, const bf16* __restrict__ Bg,
    int m0, int n0, bf16* As, bf16* Bs, f32x4 (&acc)[4][4]) {
    const int tid = threadIdx.x;
    const int lane = tid & 63, wv = tid >> 6;
    const int quad = lane >> 4, l16 = lane & 15;
    const int wr = wv >> 1, wc = wv & 1;
    const int rr = lane >> 3, cbl = lane & 7;
    const int swz = l16 & 7;
    for (int kt = 0; kt < 12; ++kt) {
        if (kt) __syncthreads();                  // prior frag reads done
        for (int c = 0; c < 4; ++c) {
            const int row = c * 32 + wv * 8 + rr;
            const int cb = cbl ^ (row & 7);       // swizzled source col-block
            const size_t gcol = (size_t)kt * 64 + cb * 8;
            async16(Ag + (size_t)(m0 + row) * 768 + gcol, As + row * 64 + cbl * 8);
            async16(Bg + (size_t)(n0 + row) * 768 + gcol, Bs + row * 64 + cbl * 8);
        }
        __syncthreads();                          // drains vmcnt, LDS visible
        for (int ks = 0; ks < 2; ++ks) {
            bf16x8 af[4], bfr[4];
            for (int t = 0; t < 4; ++t)
                af[t] = *(const bf16x8*)(As + (wr * 64 + t * 16 + l16) * 64 +
                                         (((ks * 4 + quad) ^ swz) * 8));
            for (int t = 0; t < 4; ++t)
                bfr[t] = *(const bf16x8*)(Bs + (wc * 64 + t * 16 + l16) * 64 +
                                          (((ks * 4 + quad) ^ swz) * 8));
            for (int ti = 0; ti < 4; ++ti)
                for (int tj = 0; tj < 4; ++tj)
                    acc[ti][tj] = mfma_bf16(af[ti], bfr[tj], acc[ti][tj]);
        }
    }
}

// ---------------- fused QKV projection ----------------
// z==0 (Q): scale folds 1/sqrt(DH) * log2(e) so attention can use exp2.
__global__ __launch_bounds__(256, 3) void proj_kernel(
    const bf16* __restrict__ Xq, const bf16* __restrict__ Xk, const bf16* __restrict__ Xv,
    const bf16* __restrict__ W,
    const float* __restrict__ bq, const float* __restrict__ bk, const float* __restrict__ bv,
    bf16* __restrict__ Qo, bf16* __restrict__ Ko, bf16* __restrict__ Vo) {
    __shared__ __align__(16) bf16 smem[2 * 128 * 64];
    bf16* As = smem;
    bf16* Bs = smem + 128 * 64;
    const int lin = blockIdx.x;
    const int swzb = (lin & 7) * 144 + (lin >> 3);      // bijective: 1152 % 8 == 0
    const int z = swzb / 384;
    const int rem = swzb - z * 384;
    const int rt = rem / 6;                             // row tile (0..63)
    const int xt = rem - rt * 6;                        // feature tile (0..5)
    const bf16* X = (z == 0) ? Xq : (z == 1) ? Xk : Xv;
    const bf16* Wz = W + (size_t)z * WELEM;
    const float* bias = (z == 0) ? bq : (z == 1) ? bk : bv;
    bf16* Out = (z == 0) ? Qo : (z == 1) ? Ko : Vo;

    const int tid = threadIdx.x;
    const int lane = tid & 63, wv = tid >> 6;
    const int quad = lane >> 4, l16 = lane & 15;
    const int wr = wv >> 1, wc = wv & 1;
    f32x4 acc[4][4] = {};
    int m0, n0;
    const bf16 *Ag, *Bg;
    if (z < 2) { m0 = xt * 128; n0 = rt * 128; Ag = Wz; Bg = X; }
    else       { m0 = rt * 128; n0 = xt * 128; Ag = X;  Bg = Wz; }
    gemm_core_768(Ag, Bg, m0, n0, As, Bs, acc);
    __syncthreads();                              // As/Bs reads done; reuse as Ot
    bf16* Ot = smem;                              // 128x128 bf16 tile
    if (z < 2) {
        // 0.125 * log2(e) for Q; 1.0 for K
        const float scale = (z == 0) ? 0.18033688011112042f : 1.0f;
        for (int ti = 0; ti < 4; ++ti) {
            const int featl = wr * 64 + ti * 16 + quad * 4;
            const float4 b4 = *(const float4*)(bias + m0 + featl);
            for (int tj = 0; tj < 4; ++tj) {
                const int sl = wc * 64 + tj * 16 + l16;
                bf16x4 pk;
                pk[0] = (bf16)((acc[ti][tj][0] + b4.x) * scale);
                pk[1] = (bf16)((acc[ti][tj][1] + b4.y) * scale);
                pk[2] = (bf16)((acc[ti][tj][2] + b4.z) * scale);
                pk[3] = (bf16)((acc[ti][tj][3] + b4.w) * scale);
                *(bf16x4*)&Ot[sl * 128 + featl] = pk;   // Ot[s][feat]
            }
        }
        __syncthreads();
        for (int it = 0; it < 8; ++it) {
            const int unit = it * 256 + tid;      // 16B units of the tile
            const int s = unit >> 4, u = unit & 15;
            const int feat = m0 + u * 8;
            const int hh = feat >> 6, dh = feat & 63;
            const int srow = n0 + s;
            const int bb = srow >> 11, s2 = srow & 2047;
            *(bf16x8*)&Out[((size_t)(bb * NHD + hh) * SEQ + s2) * 64 + dh] =
                *(const bf16x8*)&Ot[s * 128 + u * 8];
        }
    } else {
        for (int ti = 0; ti < 4; ++ti) {
            const int sl = wr * 64 + ti * 16 + quad * 4;
            for (int tj = 0; tj < 4; ++tj) {
                const int featl = wc * 64 + tj * 16 + l16;
                const float bv = bias[n0 + featl];
                bf16x4 pk;
                pk[0] = (bf16)(acc[ti][tj][0] + bv);
                pk[1] = (bf16)(acc[ti][tj][1] + bv);
                pk[2] = (bf16)(acc[ti][tj][2] + bv);
                pk[3] = (bf16)(acc[ti][tj][3] + bv);
                *(bf16x4*)&Ot[featl * 128 + sl] = pk;   // Ot[feat][s]
            }
        }
        __syncthreads();
        const int bb = m0 >> 11, sbase = m0 & 2047;
        for (int it = 0; it < 8; ++it) {
            const int unit = it * 256 + tid;
            const int fl = unit >> 4, u = unit & 15;
            const int feat = n0 + fl;
            const int hh = feat >> 6, dh = feat & 63;
            *(bf16x8*)&Out[((size_t)(bb * NHD + hh) * 64 + dh) * SEQ + sbase + u * 8] =
                *(const bf16x8*)&Ot[fl * 128 + u * 8];
        }
    }
}

// ---------------- flash attention (R2 structure + grafts) ----------------
// grid 768 flattened, chunked XCD swizzle (96 blocks/XCD -> 6 (b,h) K/V sets,
// 3MB < 4MB L2). block 256 = 4 waves; wave owns 32 queries for QK/softmax,
// 16 dh-rows of all 128 queries for PV. One barrier per KV tile.
// K tile: LDS double-buffer via global_load_lds (pre-swizzled source cols);
// P tile: XOR-swizzled [128][64] (2-way read conflicts = free).
__global__ __launch_bounds__(256, 3) void attn_kernel(
    const bf16* __restrict__ Qb, const bf16* __restrict__ Kb, const bf16* __restrict__ Vb,
    const int* __restrict__ mask, bf16* __restrict__ CTX) {
    __shared__ __align__(16) bf16 Ps[2][128][64];
    __shared__ __align__(16) bf16 Ks[2][64][64];
    __shared__ float alphas[2][128];
    __shared__ float invs[128];
    __shared__ int anyz_s;
    const int tid = threadIdx.x;
    const int lane = tid & 63, wv = tid >> 6, quad = lane >> 4, l16 = lane & 15;
    const int swz = l16 & 7;                 // P/K slot swizzle (row&7 == l16&7)
    // chunked XCD swizzle over 768 blocks
    const int lin = blockIdx.x;
    const int nb = (lin & 7) * 96 + (lin >> 3);
    const int qt = nb & 15;
    const int bh = nb >> 4;                  // 0..47
    const int b = bh / NHD, h = bh - b * NHD;
    if (tid == 0) anyz_s = 0;
    __syncthreads();
    {
        int4 m0v = *(const int4*)(mask + b * SEQ + tid * 8);
        int4 m1v = *(const int4*)(mask + b * SEQ + tid * 8 + 4);
        if (!(m0v.x && m0v.y && m0v.z && m0v.w && m1v.x && m1v.y && m1v.z && m1v.w))
            anyz_s = 1;
    }
    // loop-invariant Q fragments (B operand), 2 strips of 16 queries
    bf16x8 qf0[2], qf1[2];
    for (int st = 0; st < 2; ++st) {
        const bf16* qp = Qb + ((size_t)bh * SEQ + qt * 128 + wv * 32 + st * 16 + l16) * 64;
        qf0[st] = *(const bf16x8*)(qp + quad * 8);
        qf1[st] = *(const bf16x8*)(qp + 32 + quad * 8);
    }
    const bf16* Kg = Kb + (size_t)bh * SEQ * 64;                 // [s][dh]
    const bf16* Vp = Vb + (size_t)bh * 64 * SEQ + (size_t)(wv * 16 + l16) * SEQ + quad * 8;
    const int* Mp = mask + b * SEQ;
    f32x4 acc_o[8] = {};
    float rm[2] = {-1e30f, -1e30f}, rs[2] = {0.f, 0.f};

    // K staging lane geometry: LDS dest = linear base + lane*16B (HW rule);
    // global source column pre-swizzled so swizzled ds_reads see linear data.
    const int s_sub = lane >> 3;                     // 0..7 (row within 8-row strip)
    const int s_row = wv * 8 + s_sub;                // 0..31 (row within 32-row round)
    const int s_dst = (lane & 7) * 8;                // dest elem col (linear)
    const int s_src = ((lane & 7) ^ s_sub) * 8;      // source elem col (swizzled)
#define STAGE_K(BUF, K0) do {                                                  \
        async16(Kg + (size_t)((K0) + s_row) * 64 + s_src,                      \
                &Ks[BUF][s_row][s_dst]);                                       \
        async16(Kg + (size_t)((K0) + 32 + s_row) * 64 + s_src,                 \
                &Ks[BUF][32 + s_row][s_dst]);                                  \
    } while (0)

    STAGE_K(0, 0);
    __syncthreads();                         // K(0) + anyz visible (vmcnt drained)
    const int az = anyz_s;

    for (int kt = 0; kt < SEQ / 64; ++kt) {
        const int cur = kt & 1, nxt = cur ^ 1, k0 = kt * 64;
        // stage next K tile (fire-and-forget; visible at this iter's barrier)
        const int kn = (kt < SEQ / 64 - 1) ? k0 + 64 : k0;
        STAGE_K(nxt, kn);
        // V fragments (own 16 dh rows, loop-invariant addressing)
        bf16x8 vf0 = *(const bf16x8*)(Vp + k0);
        bf16x8 vf1 = *(const bf16x8*)(Vp + k0 + 32);
        // K fragments from LDS (swizzled slots)
        bf16x8 kf0[4], kf1[4];
        #pragma unroll
        for (int jj = 0; jj < 4; ++jj) {
            const bf16* kr = &Ks[cur][jj * 16 + l16][0];
            kf0[jj] = *(const bf16x8*)(kr + ((quad ^ swz) * 8));
            kf1[jj] = *(const bf16x8*)(kr + (((4 + quad) ^ swz) * 8));
        }
        // per-strip: QK^T, softmax (exp2 domain), P store (swizzled), rescale
        #pragma unroll
        for (int st = 0; st < 2; ++st) {
            f32x4 sc[4];
            #pragma unroll
            for (int jj = 0; jj < 4; ++jj) {
                f32x4 zf = {};
                zf = mfma_bf16(kf0[jj], qf0[st], zf);
                sc[jj] = mfma_bf16(kf1[jj], qf1[st], zf);
            }
            if (az) {
                #pragma unroll
                for (int jj = 0; jj < 4; ++jj) {
                    const int4 mm = *(const int4*)(Mp + k0 + jj * 16 + quad * 4);
                    sc[jj][0] += mm.x ? 0.f : -1e30f;
                    sc[jj][1] += mm.y ? 0.f : -1e30f;
                    sc[jj][2] += mm.z ? 0.f : -1e30f;
                    sc[jj][3] += mm.w ? 0.f : -1e30f;
                }
            }
            float tmax = -1e30f;
            #pragma unroll
            for (int jj = 0; jj < 4; ++jj)
                #pragma unroll
                for (int r = 0; r < 4; ++r) tmax = fmaxf(tmax, sc[jj][r]);
            tmax = fmaxf(tmax, __shfl_xor(tmax, 16));
            tmax = fmaxf(tmax, __shfl_xor(tmax, 32));
            const float nmax = fmaxf(rm[st], tmax);
            const float alpha = exp2f(rm[st] - nmax);
            rm[st] = nmax;
            float tsum = 0.f;
            bf16* prow = &Ps[cur][wv * 32 + st * 16 + l16][0];
            #pragma unroll
            for (int jj = 0; jj < 4; ++jj) {
                bf16x4 pk;
                #pragma unroll
                for (int r = 0; r < 4; ++r) {
                    const float p = exp2f(sc[jj][r] - nmax);
                    tsum += p;
                    pk[r] = (bf16)p;
                }
                *(bf16x4*)&prow[(jj * 16 + quad * 4) ^ (swz * 8)] = pk;
            }
            tsum += __shfl_xor(tsum, 16);
            tsum += __shfl_xor(tsum, 32);
            rs[st] = rs[st] * alpha + tsum;
            if (lane < 16) alphas[cur][wv * 32 + st * 16 + lane] = alpha;
        }
        __syncthreads();                     // Ps/alphas[cur] + K(nxt) visible
        // PV: each wave computes its 16 dh rows for all 128 queries
        #pragma unroll
        for (int qj = 0; qj < 8; ++qj) {
            const float al = alphas[cur][qj * 16 + l16];
            f32x4 c = acc_o[qj];
            c[0] *= al; c[1] *= al; c[2] *= al; c[3] *= al;
            const bf16* pr = &Ps[cur][qj * 16 + l16][0];
            bf16x8 pf0 = *(const bf16x8*)(pr + ((quad ^ swz) * 8));
            bf16x8 pf1 = *(const bf16x8*)(pr + (((4 + quad) ^ swz) * 8));
            c = mfma_bf16(vf0, pf0, c);
            c = mfma_bf16(vf1, pf1, c);
            acc_o[qj] = c;
        }
    }
#undef STAGE_K

    if (lane < 16) {
        invs[wv * 32 + lane] = 1.0f / rs[0];
        invs[wv * 32 + 16 + lane] = 1.0f / rs[1];
    }
    __syncthreads();
    for (int qj = 0; qj < 8; ++qj) {
        const float inv = invs[qj * 16 + l16];
        bf16x4 pk;
        for (int r = 0; r < 4; ++r) pk[r] = (bf16)(acc_o[qj][r] * inv);
        const int s = qt * 128 + qj * 16 + l16;
        *(bf16x4*)&CTX[(size_t)(b * SEQ + s) * DIMD + h * 64 + wv * 16 + quad * 4] = pk;
    }
}

// ---------------- output projection (XCD-swizzled, ctx-panel-sharing order) ----------------
__global__ __launch_bounds__(256, 3) void oproj_kernel(
    const bf16* __restrict__ ctx, const bf16* __restrict__ wo,
    const float* __restrict__ bo, float* __restrict__ out) {
    __shared__ __align__(16) bf16 smem[2 * 128 * 64];
    const int lin = blockIdx.x;
    const int swzb = (lin & 7) * 48 + (lin >> 3);       // bijective: 384 % 8 == 0
    const int rt = swzb / 6;                            // ctx row tile (0..63)
    const int xt = swzb - rt * 6;                       // feature tile (0..5)
    const int tid = threadIdx.x;
    const int lane = tid & 63, wv = tid >> 6;
    const int quad = lane >> 4, l16 = lane & 15;
    const int wr = wv >> 1, wc = wv & 1;
    const int m0 = rt * 128, n0 = xt * 128;
    f32x4 acc[4][4] = {};
    gemm_core_768(ctx, wo, m0, n0, smem, smem + 128 * 64, acc);
    for (int ti = 0; ti < 4; ++ti) {
        const int rowb = m0 + wr * 64 + ti * 16 + quad * 4;
        for (int tj = 0; tj < 4; ++tj) {
            const int feat = n0 + wc * 64 + tj * 16 + l16;
            const float bv = bo[feat];
            for (int r = 0; r < 4; ++r)
                out[(size_t)(rowb + r) * DIMD + feat] = acc[ti][tj][r] + bv;
        }
    }
}

extern "C" void kernel_launch(void* const* d_in, const int* in_sizes, int n_in,
                              void* d_out, int out_size, void* d_ws, size_t ws_size,
                              hipStream_t stream) {
    const float* query = (const float*)d_in[0];
    const float* key_t = (const float*)d_in[1];
    const float* value = (const float*)d_in[2];
    const int*   mask  = (const int*)d_in[3];
    const float* q_w = (const float*)d_in[4];
    const float* q_b = (const float*)d_in[5];
    const float* k_w = (const float*)d_in[6];
    const float* k_b = (const float*)d_in[7];
    const float* v_w = (const float*)d_in[8];
    const float* v_b = (const float*)d_in[9];
    const float* o_w = (const float*)d_in[10];
    const float* o_b = (const float*)d_in[11];
    float* out = (float*)d_out;

    bf16* ws  = (bf16*)d_ws;
    bf16* W   = ws;                                  // 4 x WELEM
    bf16* XBq = ws + (size_t)4 * WELEM;              // bf16 inputs
    bf16* XBk = XBq + (size_t)MTOT * DIMD;
    bf16* XBv = XBk + (size_t)MTOT * DIMD;
    bf16* Qb  = XBv + (size_t)MTOT * DIMD;           // [b][h][s][dh]
    bf16* Kb  = Qb + (size_t)MTOT * DIMD;            // [b][h][s][dh]
    bf16* Vb  = Kb + (size_t)MTOT * DIMD;            // [b][h][dh][s]
    bf16* CTX = XBq;                                 // alias: XBq dead after proj

    convert_all_kernel<<<2304 + 3 * 6144, 256, 0, stream>>>(
        q_w, k_w, v_w, o_w, query, key_t, value, W, XBq, XBk, XBv);

    proj_kernel<<<1152, 256, 0, stream>>>(XBq, XBk, XBv, W, q_b, k_b, v_b, Qb, Kb, Vb);

    attn_kernel<<<768, 256, 0, stream>>>(Qb, Kb, Vb, mask, CTX);
    oproj_kernel<<<384, 256, 0, stream>>>(CTX, W + (size_t)3 * WELEM, o_b, out);
}